// Round 3
// baseline (424.370 us; speedup 1.0000x reference)
//
#include <hip/hip_runtime.h>
#include <hip/hip_bf16.h>

// LoRAConv1D: out[8192][4800] = x@W + b + 4.0*(x@A)@B
// Rank-8 LoRA folded into GEMM K dim (K'=1664=26*64), bf16 MFMA.
// R3: gemm rebuilt as 256x160 tile, 8 waves, TRIPLE-buffered LDS with
// counted vmcnt (T3+T4): stage(t+2) issued before compute(t), so
// global_load_lds stays in flight across 2 compute phases instead of
// draining at every barrier (the m97-structure ~900TF ceiling).
// + XCD-aware block swizzle (960 = 8*120) + setprio around MFMA.
// Inner fragment/swizzle/MFMA body transplanted verbatim from the
// verified R2 kernel (identical accumulation order).

#define M_ROWS 8192
#define K_DIM  1600
#define N_DIM  4800
#define KP     1664   // 1600 + 8 (lora) + 56 zero pad = 26*64

#define BM 256
#define BN 160
#define BK 64
#define KT (KP / BK)  // 26

// fused prep grid split
#define NXB 1024              // x path: 8 rows/block (2 per wave)
#define NWB (75 * 50)         // W path: 64n x 32k tiles
#define NLB 19                // lora_B path: ceil(4800/256)

typedef __attribute__((ext_vector_type(4))) float f32x4;
typedef __attribute__((ext_vector_type(8))) short s16x8;

static __device__ __forceinline__ unsigned short f2bf(float f) {
    unsigned int u = __float_as_uint(f);
    u += 0x7fffu + ((u >> 16) & 1u);
    return (unsigned short)(u >> 16);
}

typedef __attribute__((address_space(3))) unsigned int as3_uint;
typedef __attribute__((address_space(1))) const unsigned int as1_uint;

static __device__ __forceinline__ void gl16(const unsigned short* g,
                                            unsigned short* l) {
    __builtin_amdgcn_global_load_lds((as1_uint*)g, (as3_uint*)l, 16, 0, 0);
}

// ---------------------------------------------------------------------------
// prep_all: one kernel, three block-ranges.  (unchanged from R2, verified)
//   [0, NXB)           : x -> bf16 cast + rank-8 x@A tail   (no LDS)
//   [NXB, NXB+NWB)     : W fp32 [1600][4800] -> Wtp bf16 [4800][KP] transpose
//   [NXB+NWB, +NLB)    : Wtp[n][1600..1607] = bf16(4*lora_B[r][n]); rest 0
// ---------------------------------------------------------------------------
__global__ __launch_bounds__(256) void prep_all(const float* __restrict__ x,
                                                const float* __restrict__ W,
                                                const float* __restrict__ lora_A,
                                                const float* __restrict__ lora_B,
                                                unsigned short* __restrict__ Xbp,
                                                unsigned short* __restrict__ Wtp) {
    __shared__ float tile[32][65];
    const int bid = blockIdx.x;
    const int t   = threadIdx.x;

    if (bid < NXB) {
        // ---- x path: 2 rows per wave, A from global (L2-resident) ----
        const int lane = t & 63;
        const int w    = t >> 6;
        const int m0   = bid * 8 + w * 2;
        const float* xr0 = x + (size_t)m0 * K_DIM;
        const float* xr1 = xr0 + K_DIM;
        unsigned short* o0 = Xbp + (size_t)m0 * KP;
        unsigned short* o1 = o0 + KP;

        float a0[8], a1[8];
#pragma unroll
        for (int r = 0; r < 8; ++r) { a0[r] = 0.f; a1[r] = 0.f; }

        for (int g = lane; g < 400; g += 64) {
            const float4* ap = (const float4*)(lora_A + (size_t)32 * g);
            float4 x0 = ((const float4*)xr0)[g];
            float4 x1 = ((const float4*)xr1)[g];

            ushort4 s0, s1;
            s0.x = f2bf(x0.x); s0.y = f2bf(x0.y); s0.z = f2bf(x0.z); s0.w = f2bf(x0.w);
            s1.x = f2bf(x1.x); s1.y = f2bf(x1.y); s1.z = f2bf(x1.z); s1.w = f2bf(x1.w);
            ((ushort4*)o0)[g] = s0;
            ((ushort4*)o1)[g] = s1;

            float xs0[4] = {x0.x, x0.y, x0.z, x0.w};
            float xs1[4] = {x1.x, x1.y, x1.z, x1.w};
#pragma unroll
            for (int j = 0; j < 4; ++j) {
                float4 lo = ap[2 * j + 0];
                float4 hi = ap[2 * j + 1];
                a0[0] += xs0[j] * lo.x; a0[1] += xs0[j] * lo.y;
                a0[2] += xs0[j] * lo.z; a0[3] += xs0[j] * lo.w;
                a0[4] += xs0[j] * hi.x; a0[5] += xs0[j] * hi.y;
                a0[6] += xs0[j] * hi.z; a0[7] += xs0[j] * hi.w;
                a1[0] += xs1[j] * lo.x; a1[1] += xs1[j] * lo.y;
                a1[2] += xs1[j] * lo.z; a1[3] += xs1[j] * lo.w;
                a1[4] += xs1[j] * hi.x; a1[5] += xs1[j] * hi.y;
                a1[6] += xs1[j] * hi.z; a1[7] += xs1[j] * hi.w;
            }
        }

#pragma unroll
        for (int off = 1; off < 64; off <<= 1) {
#pragma unroll
            for (int r = 0; r < 8; ++r) {
                a0[r] += __shfl_xor(a0[r], off, 64);
                a1[r] += __shfl_xor(a1[r], off, 64);
            }
        }

        if (lane < 16) {   // tail groups 400..415: [x@A | zeros]
            ushort4 t0, t1;
            t0.x = 0; t0.y = 0; t0.z = 0; t0.w = 0;
            t1 = t0;
            if (lane == 0) {
                t0.x = f2bf(a0[0]); t0.y = f2bf(a0[1]); t0.z = f2bf(a0[2]); t0.w = f2bf(a0[3]);
                t1.x = f2bf(a1[0]); t1.y = f2bf(a1[1]); t1.z = f2bf(a1[2]); t1.w = f2bf(a1[3]);
            } else if (lane == 1) {
                t0.x = f2bf(a0[4]); t0.y = f2bf(a0[5]); t0.z = f2bf(a0[6]); t0.w = f2bf(a0[7]);
                t1.x = f2bf(a1[4]); t1.y = f2bf(a1[5]); t1.z = f2bf(a1[6]); t1.w = f2bf(a1[7]);
            }
            ((ushort4*)o0)[400 + lane] = t0;
            ((ushort4*)o1)[400 + lane] = t1;
        }
        return;
    }

    if (bid < NXB + NWB) {
        // ---- W transpose path ----
        const int wid = bid - NXB;
        const int n0  = (wid % 75) * 64;
        const int k0  = (wid / 75) * 32;

#pragma unroll
        for (int p = 0; p < 2; ++p) {
            const int k  = p * 16 + (t >> 4);
            const int c4 = (t & 15) * 4;
            float4 v = *(const float4*)(W + (size_t)(k0 + k) * N_DIM + n0 + c4);
            tile[k][c4 + 0] = v.x; tile[k][c4 + 1] = v.y;
            tile[k][c4 + 2] = v.z; tile[k][c4 + 3] = v.w;
        }
        __syncthreads();

        const int n   = t >> 2;
        const int seg = t & 3;
        unsigned int pk[4];
#pragma unroll
        for (int h = 0; h < 4; ++h) {
            unsigned int lo = f2bf(tile[seg * 8 + 2 * h + 0][n]);
            unsigned int hi = f2bf(tile[seg * 8 + 2 * h + 1][n]);
            pk[h] = lo | (hi << 16);
        }
        uint4 o = {pk[0], pk[1], pk[2], pk[3]};
        *(uint4*)(Wtp + (size_t)(n0 + n) * KP + k0 + seg * 8) = o;
        return;
    }

    // ---- lora_B path ----
    {
        const int lid = bid - (NXB + NWB);
        const int n = lid * 256 + t;
        if (n >= N_DIM) return;
        ushort4* d4 = (ushort4*)(Wtp + (size_t)n * KP + 1600);
        ushort4 o0, o1, z;
        o0.x = f2bf(4.0f * lora_B[0 * N_DIM + n]);
        o0.y = f2bf(4.0f * lora_B[1 * N_DIM + n]);
        o0.z = f2bf(4.0f * lora_B[2 * N_DIM + n]);
        o0.w = f2bf(4.0f * lora_B[3 * N_DIM + n]);
        o1.x = f2bf(4.0f * lora_B[4 * N_DIM + n]);
        o1.y = f2bf(4.0f * lora_B[5 * N_DIM + n]);
        o1.z = f2bf(4.0f * lora_B[6 * N_DIM + n]);
        o1.w = f2bf(4.0f * lora_B[7 * N_DIM + n]);
        z.x = 0; z.y = 0; z.z = 0; z.w = 0;
        d4[0] = o0;
        d4[1] = o1;
#pragma unroll
        for (int i = 2; i < 16; ++i) d4[i] = z;
    }
}

// ---------------------------------------------------------------------------
// gemm_bt: C[m][n] = sum_k Ab[m][k]*Bb[n][k] + bias[n]
// 256x160 tile, 8 waves (4M x 2N), wave tile 64x80 (4x5 MFMA tiles).
// Triple-buffered LDS (156 KB), counted vmcnt pipeline:
//   iter t: issue stage(t+2) -> buf[(t+2)%3]; compute buf[t%3];
//           s_waitcnt vmcnt(I) (I = own stage(t+2) issues -> stage(t+1)
//           fully landed); s_barrier.
// LDS layout (swizzled, unchanged): row r, kgroup g stored at elem
//   r*64 + (g ^ (r&7))*8; swizzle applied on SOURCE global address.
// ---------------------------------------------------------------------------
__global__ __launch_bounds__(512, 2) void gemm_bt(const unsigned short* __restrict__ Ab,
                                                  const unsigned short* __restrict__ Bb,
                                                  const float* __restrict__ bias,
                                                  float* __restrict__ out) {
    __shared__ unsigned short lsA[3][BM * BK];   // 3 x 32 KB
    __shared__ unsigned short lsB[3][BN * BK];   // 3 x 20 KB   (total 156 KB)

    const int t    = threadIdx.x;
    const int lane = t & 63;
    const int w    = t >> 6;                 // 0..7

    // XCD-aware bijective swizzle: 960 blocks = 8 XCDs * 120
    const int orig = blockIdx.x;
    const int swz  = (orig & 7) * 120 + (orig >> 3);
    const int n0   = (swz % 30) * BN;
    const int m0   = (swz / 30) * BM;

    const int wr   = (w >> 1) * 64;          // 0,64,128,192
    const int wc   = (w & 1) * 80;           // 0,80
    const int lr   = lane & 15;
    const int quad = lane >> 4;
    const int lx   = lr & 7;

    // staging source addressing (swizzled kgroup), chunk = 8 rows x 64 k
    const int rS = lane >> 3;                        // 0..7 within chunk
    const int gS = ((lane & 7) ^ (rS & 7)) * 8;      // source k offset
    const unsigned short* srcA = Ab + (size_t)(m0 + rS) * KP + gS;
    const unsigned short* srcB = Bb + (size_t)(n0 + rS) * KP + gS;
    // issues per wave per tile: A 32 chunks (4 each) + B 20 chunks
    // (waves 0-3: 3, waves 4-7: 2)  ->  I = 7 (w<4) or 6 (w>=4)
    const bool wlow = (w < 4);

    int rowA[4], rowB[5];
#pragma unroll
    for (int mt = 0; mt < 4; ++mt) rowA[mt] = (wr + mt * 16 + lr) * BK;
#pragma unroll
    for (int nt = 0; nt < 5; ++nt) rowB[nt] = (wc + nt * 16 + lr) * BK;

    f32x4 acc[4][5];
#pragma unroll
    for (int mt = 0; mt < 4; ++mt)
#pragma unroll
        for (int nt = 0; nt < 5; ++nt) acc[mt][nt] = (f32x4)0.f;

#define STAGE(ktile, buf)                                                     \
    do {                                                                      \
        const int kb_ = (ktile) * BK;                                         \
        _Pragma("unroll")                                                     \
        for (int c = w; c < 32; c += 8)                                       \
            gl16(srcA + (size_t)c * 8 * KP + kb_, &lsA[(buf)][c * 512]);      \
        _Pragma("unroll")                                                     \
        for (int c = w; c < 20; c += 8)                                       \
            gl16(srcB + (size_t)c * 8 * KP + kb_, &lsB[(buf)][c * 512]);      \
    } while (0)

    // prologue: stage tiles 0,1; drain tile-0 issues only (counted)
    STAGE(0, 0);
    STAGE(1, 1);
    if (wlow) asm volatile("s_waitcnt vmcnt(7)" ::: "memory");
    else      asm volatile("s_waitcnt vmcnt(6)" ::: "memory");
    __builtin_amdgcn_sched_barrier(0);
    __builtin_amdgcn_s_barrier();

    int cb = 0, sb = 2;
    for (int kt = 0; kt < KT; ++kt) {
        if (kt + 2 < KT) STAGE(kt + 2, sb);

        const unsigned short* bA = &lsA[cb][0];
        const unsigned short* bB = &lsB[cb][0];
#pragma unroll
        for (int ksub = 0; ksub < 2; ++ksub) {
            const int g0 = quad + ksub * 4;
            const int koff = (g0 ^ lx) * 8;
            s16x8 af[4], bf[5];
#pragma unroll
            for (int mt = 0; mt < 4; ++mt) af[mt] = *(const s16x8*)&bA[rowA[mt] + koff];
#pragma unroll
            for (int nt = 0; nt < 5; ++nt) bf[nt] = *(const s16x8*)&bB[rowB[nt] + koff];
            __builtin_amdgcn_s_setprio(1);
#pragma unroll
            for (int mt = 0; mt < 4; ++mt)
#pragma unroll
                for (int nt = 0; nt < 5; ++nt)
                    acc[mt][nt] = __builtin_amdgcn_mfma_f32_16x16x32_bf16(
                        af[mt], bf[nt], acc[mt][nt], 0, 0, 0);
            __builtin_amdgcn_s_setprio(0);
        }

        // stage(kt+1) must be fully landed before next iter reads it:
        // outstanding = stage(kt+1) + stage(kt+2)(if issued); leave only
        // the newer group in flight.
        if (kt < KT - 2) {
            if (wlow) asm volatile("s_waitcnt vmcnt(7)" ::: "memory");
            else      asm volatile("s_waitcnt vmcnt(6)" ::: "memory");
        } else {
            asm volatile("s_waitcnt vmcnt(0)" ::: "memory");
        }
        __builtin_amdgcn_sched_barrier(0);
        __builtin_amdgcn_s_barrier();

        cb = (cb == 2) ? 0 : cb + 1;
        sb = (sb == 2) ? 0 : sb + 1;
    }
#undef STAGE

    // epilogue: C/D layout col=lane&15, row=(lane>>4)*4+reg
#pragma unroll
    for (int nt = 0; nt < 5; ++nt) {
        const int gc = n0 + wc + nt * 16 + lr;
        const float bv = bias[gc];
#pragma unroll
        for (int mt = 0; mt < 4; ++mt) {
#pragma unroll
            for (int r = 0; r < 4; ++r) {
                const int grow = m0 + wr + mt * 16 + quad * 4 + r;
                out[(size_t)grow * N_DIM + gc] = acc[mt][nt][r] + bv;
            }
        }
    }
}

// ---------------------------------------------------------------------------
extern "C" void kernel_launch(void* const* d_in, const int* in_sizes, int n_in,
                              void* d_out, int out_size, void* d_ws, size_t ws_size,
                              hipStream_t stream) {
    const float* x      = (const float*)d_in[0];
    const float* W      = (const float*)d_in[1];
    const float* b      = (const float*)d_in[2];
    const float* lora_A = (const float*)d_in[3];
    const float* lora_B = (const float*)d_in[4];
    float* out = (float*)d_out;

    unsigned short* Xbp = (unsigned short*)d_ws;              // 8192*1664 bf16
    unsigned short* Wtp = Xbp + (size_t)M_ROWS * KP;          // 4800*1664 bf16
    // ws bytes: (8192+4800)*1664*2 = 43,225,088

    prep_all<<<NXB + NWB + NLB, 256, 0, stream>>>(x, W, lora_A, lora_B, Xbp, Wtp);
    gemm_bt<<<dim3((N_DIM / BN) * (M_ROWS / BM)), 512, 0, stream>>>(Xbp, Wtp, b, out);
}

// Round 5
// 387.478 us; speedup vs baseline: 1.0952x; 1.0952x over previous
//
#include <hip/hip_runtime.h>
#include <hip/hip_bf16.h>

// LoRAConv1D: out[8192][4800] = x@W + b + 4.0*(x@A)@B
// Rank-8 LoRA folded into GEMM K dim (K'=1664=26*64), bf16 MFMA.
// R4 (resubmit after infra failure): verified R2 gemm structure (128x160,
// 4 waves, same fragment/swizzle/MFMA body) with two deltas:
//  (a) double-buffered LDS (72 KB, 2 blocks/CU) + issue-early staging:
//      STAGE(kt+1 -> other buf) BEFORE compute(kt); ONE __syncthreads per
//      iter (its implicit vmcnt(0) drain now lands loads that had a full
//      compute phase to fly). Simpler sync than R2 (1 barrier vs 2).
//  (b) XCD-aware bijective block swizzle (1920 = 8*240; per-XCD chunk =
//      8 m-rows x 30 n, n-fastest) for A-panel L2 locality.
// R3 post-mortem: 512-thr/156KB/1-block-CU pipeline lost cross-block
// overlap (m196's coarse-split-regression reproduced); reverted.

#define M_ROWS 8192
#define K_DIM  1600
#define N_DIM  4800
#define KP     1664   // 1600 + 8 (lora) + 56 zero pad = 26*64

#define BM 128
#define BN 160
#define BK 64
#define KT (KP / BK)  // 26

// fused prep grid split
#define NXB 1024              // x path: 8 rows/block (2 per wave)
#define NWB (75 * 50)         // W path: 64n x 32k tiles
#define NLB 19                // lora_B path: ceil(4800/256)

typedef __attribute__((ext_vector_type(4))) float f32x4;
typedef __attribute__((ext_vector_type(8))) short s16x8;

static __device__ __forceinline__ unsigned short f2bf(float f) {
    unsigned int u = __float_as_uint(f);
    u += 0x7fffu + ((u >> 16) & 1u);
    return (unsigned short)(u >> 16);
}

typedef __attribute__((address_space(3))) unsigned int as3_uint;
typedef __attribute__((address_space(1))) const unsigned int as1_uint;

static __device__ __forceinline__ void gl16(const unsigned short* g,
                                            unsigned short* l) {
    __builtin_amdgcn_global_load_lds((as1_uint*)g, (as3_uint*)l, 16, 0, 0);
}

// ---------------------------------------------------------------------------
// prep_all: one kernel, three block-ranges.  (unchanged from R2, verified)
//   [0, NXB)           : x -> bf16 cast + rank-8 x@A tail   (no LDS)
//   [NXB, NXB+NWB)     : W fp32 [1600][4800] -> Wtp bf16 [4800][KP] transpose
//   [NXB+NWB, +NLB)    : Wtp[n][1600..1607] = bf16(4*lora_B[r][n]); rest 0
// ---------------------------------------------------------------------------
__global__ __launch_bounds__(256) void prep_all(const float* __restrict__ x,
                                                const float* __restrict__ W,
                                                const float* __restrict__ lora_A,
                                                const float* __restrict__ lora_B,
                                                unsigned short* __restrict__ Xbp,
                                                unsigned short* __restrict__ Wtp) {
    __shared__ float tile[32][65];
    const int bid = blockIdx.x;
    const int t   = threadIdx.x;

    if (bid < NXB) {
        // ---- x path: 2 rows per wave, A from global (L2-resident) ----
        const int lane = t & 63;
        const int w    = t >> 6;
        const int m0   = bid * 8 + w * 2;
        const float* xr0 = x + (size_t)m0 * K_DIM;
        const float* xr1 = xr0 + K_DIM;
        unsigned short* o0 = Xbp + (size_t)m0 * KP;
        unsigned short* o1 = o0 + KP;

        float a0[8], a1[8];
#pragma unroll
        for (int r = 0; r < 8; ++r) { a0[r] = 0.f; a1[r] = 0.f; }

        for (int g = lane; g < 400; g += 64) {
            const float4* ap = (const float4*)(lora_A + (size_t)32 * g);
            float4 x0 = ((const float4*)xr0)[g];
            float4 x1 = ((const float4*)xr1)[g];

            ushort4 s0, s1;
            s0.x = f2bf(x0.x); s0.y = f2bf(x0.y); s0.z = f2bf(x0.z); s0.w = f2bf(x0.w);
            s1.x = f2bf(x1.x); s1.y = f2bf(x1.y); s1.z = f2bf(x1.z); s1.w = f2bf(x1.w);
            ((ushort4*)o0)[g] = s0;
            ((ushort4*)o1)[g] = s1;

            float xs0[4] = {x0.x, x0.y, x0.z, x0.w};
            float xs1[4] = {x1.x, x1.y, x1.z, x1.w};
#pragma unroll
            for (int j = 0; j < 4; ++j) {
                float4 lo = ap[2 * j + 0];
                float4 hi = ap[2 * j + 1];
                a0[0] += xs0[j] * lo.x; a0[1] += xs0[j] * lo.y;
                a0[2] += xs0[j] * lo.z; a0[3] += xs0[j] * lo.w;
                a0[4] += xs0[j] * hi.x; a0[5] += xs0[j] * hi.y;
                a0[6] += xs0[j] * hi.z; a0[7] += xs0[j] * hi.w;
                a1[0] += xs1[j] * lo.x; a1[1] += xs1[j] * lo.y;
                a1[2] += xs1[j] * lo.z; a1[3] += xs1[j] * lo.w;
                a1[4] += xs1[j] * hi.x; a1[5] += xs1[j] * hi.y;
                a1[6] += xs1[j] * hi.z; a1[7] += xs1[j] * hi.w;
            }
        }

#pragma unroll
        for (int off = 1; off < 64; off <<= 1) {
#pragma unroll
            for (int r = 0; r < 8; ++r) {
                a0[r] += __shfl_xor(a0[r], off, 64);
                a1[r] += __shfl_xor(a1[r], off, 64);
            }
        }

        if (lane < 16) {   // tail groups 400..415: [x@A | zeros]
            ushort4 t0, t1;
            t0.x = 0; t0.y = 0; t0.z = 0; t0.w = 0;
            t1 = t0;
            if (lane == 0) {
                t0.x = f2bf(a0[0]); t0.y = f2bf(a0[1]); t0.z = f2bf(a0[2]); t0.w = f2bf(a0[3]);
                t1.x = f2bf(a1[0]); t1.y = f2bf(a1[1]); t1.z = f2bf(a1[2]); t1.w = f2bf(a1[3]);
            } else if (lane == 1) {
                t0.x = f2bf(a0[4]); t0.y = f2bf(a0[5]); t0.z = f2bf(a0[6]); t0.w = f2bf(a0[7]);
                t1.x = f2bf(a1[4]); t1.y = f2bf(a1[5]); t1.z = f2bf(a1[6]); t1.w = f2bf(a1[7]);
            }
            ((ushort4*)o0)[400 + lane] = t0;
            ((ushort4*)o1)[400 + lane] = t1;
        }
        return;
    }

    if (bid < NXB + NWB) {
        // ---- W transpose path ----
        const int wid = bid - NXB;
        const int n0  = (wid % 75) * 64;
        const int k0  = (wid / 75) * 32;

#pragma unroll
        for (int p = 0; p < 2; ++p) {
            const int k  = p * 16 + (t >> 4);
            const int c4 = (t & 15) * 4;
            float4 v = *(const float4*)(W + (size_t)(k0 + k) * N_DIM + n0 + c4);
            tile[k][c4 + 0] = v.x; tile[k][c4 + 1] = v.y;
            tile[k][c4 + 2] = v.z; tile[k][c4 + 3] = v.w;
        }
        __syncthreads();

        const int n   = t >> 2;
        const int seg = t & 3;
        unsigned int pk[4];
#pragma unroll
        for (int h = 0; h < 4; ++h) {
            unsigned int lo = f2bf(tile[seg * 8 + 2 * h + 0][n]);
            unsigned int hi = f2bf(tile[seg * 8 + 2 * h + 1][n]);
            pk[h] = lo | (hi << 16);
        }
        uint4 o = {pk[0], pk[1], pk[2], pk[3]};
        *(uint4*)(Wtp + (size_t)(n0 + n) * KP + k0 + seg * 8) = o;
        return;
    }

    // ---- lora_B path ----
    {
        const int lid = bid - (NXB + NWB);
        const int n = lid * 256 + t;
        if (n >= N_DIM) return;
        ushort4* d4 = (ushort4*)(Wtp + (size_t)n * KP + 1600);
        ushort4 o0, o1, z;
        o0.x = f2bf(4.0f * lora_B[0 * N_DIM + n]);
        o0.y = f2bf(4.0f * lora_B[1 * N_DIM + n]);
        o0.z = f2bf(4.0f * lora_B[2 * N_DIM + n]);
        o0.w = f2bf(4.0f * lora_B[3 * N_DIM + n]);
        o1.x = f2bf(4.0f * lora_B[4 * N_DIM + n]);
        o1.y = f2bf(4.0f * lora_B[5 * N_DIM + n]);
        o1.z = f2bf(4.0f * lora_B[6 * N_DIM + n]);
        o1.w = f2bf(4.0f * lora_B[7 * N_DIM + n]);
        z.x = 0; z.y = 0; z.z = 0; z.w = 0;
        d4[0] = o0;
        d4[1] = o1;
#pragma unroll
        for (int i = 2; i < 16; ++i) d4[i] = z;
    }
}

// ---------------------------------------------------------------------------
// gemm_bt: C[m][n] = sum_k Ab[m][k]*Bb[n][k] + bias[n]
// 128x160 tile, 4 waves (2x2), wave tile 64x80 = 4x5 MFMA tiles.
// Double-buffered LDS (72 KB, 2 blocks/CU), issue-early staging:
//   iter kt: STAGE(kt+1 -> buf^1); compute buf; __syncthreads(); flip.
// The __syncthreads' implicit vmcnt(0) drain lands stage(kt+1) loads that
// overlapped the whole compute phase. One barrier per iter (R2 had two).
// LDS layout (swizzled): row r, kgroup g stored at elem r*64 + (g^(r&7))*8;
// swizzle applied on SOURCE global address (gl_lds dst must stay linear).
// Fragment ds_read_b128 -> 2-way bank alias only (free).
// XCD swizzle: 1920 blocks = 8 XCDs x 240 (8 m-rows x 30 n, n fastest).
// ---------------------------------------------------------------------------
__global__ __launch_bounds__(256, 2) void gemm_bt(const unsigned short* __restrict__ Ab,
                                                  const unsigned short* __restrict__ Bb,
                                                  const float* __restrict__ bias,
                                                  float* __restrict__ out) {
    __shared__ unsigned short lsA[2][BM * BK];   // 2 x 16 KB
    __shared__ unsigned short lsB[2][BN * BK];   // 2 x 20 KB  (72 KB total)

    const int t    = threadIdx.x;
    const int lane = t & 63;
    const int w    = t >> 6;

    // XCD-aware bijective swizzle: 1920 = 8 * 240
    const int bid  = blockIdx.x;
    const int swz  = (bid & 7) * 240 + (bid >> 3);
    const int m0   = (swz / 30) * BM;
    const int n0   = (swz % 30) * BN;

    const int wr   = (w >> 1) * 64;
    const int wc   = (w & 1) * 80;
    const int lr   = lane & 15;
    const int quad = lane >> 4;
    const int lx   = lr & 7;

    // staging source addressing (swizzled kgroup), chunk = 8 rows x 64 k
    const int rS = lane >> 3;                        // 0..7 within chunk
    const int gS = ((lane & 7) ^ (rS & 7)) * 8;      // source k offset
    const unsigned short* srcA = Ab + (size_t)(m0 + rS) * KP + gS;
    const unsigned short* srcB = Bb + (size_t)(n0 + rS) * KP + gS;

    int rowA[4], rowB[5];
#pragma unroll
    for (int mt = 0; mt < 4; ++mt) rowA[mt] = (wr + mt * 16 + lr) * BK;
#pragma unroll
    for (int nt = 0; nt < 5; ++nt) rowB[nt] = (wc + nt * 16 + lr) * BK;

    f32x4 acc[4][5];
#pragma unroll
    for (int mt = 0; mt < 4; ++mt)
#pragma unroll
        for (int nt = 0; nt < 5; ++nt) acc[mt][nt] = (f32x4)0.f;

#define STAGE(ktile, buf)                                                     \
    do {                                                                      \
        const int kb_ = (ktile) * BK;                                         \
        _Pragma("unroll")                                                     \
        for (int c = w; c < 16; c += 4)                                       \
            gl16(srcA + (size_t)c * 8 * KP + kb_, &lsA[(buf)][c * 512]);      \
        _Pragma("unroll")                                                     \
        for (int c = w; c < 20; c += 4)                                       \
            gl16(srcB + (size_t)c * 8 * KP + kb_, &lsB[(buf)][c * 512]);      \
    } while (0)

    STAGE(0, 0);
    __syncthreads();   // implicit vmcnt(0): tile 0 landed

    int cur = 0;
    for (int kt = 0; kt < KT; ++kt) {
        if (kt + 1 < KT) STAGE(kt + 1, cur ^ 1);   // overlap with compute

        const unsigned short* bA = &lsA[cur][0];
        const unsigned short* bB = &lsB[cur][0];
#pragma unroll
        for (int ksub = 0; ksub < 2; ++ksub) {
            const int g0 = quad + ksub * 4;
            const int koff = (g0 ^ lx) * 8;
            s16x8 af[4], bf[5];
#pragma unroll
            for (int mt = 0; mt < 4; ++mt) af[mt] = *(const s16x8*)&bA[rowA[mt] + koff];
#pragma unroll
            for (int nt = 0; nt < 5; ++nt) bf[nt] = *(const s16x8*)&bB[rowB[nt] + koff];
#pragma unroll
            for (int mt = 0; mt < 4; ++mt)
#pragma unroll
                for (int nt = 0; nt < 5; ++nt)
                    acc[mt][nt] = __builtin_amdgcn_mfma_f32_16x16x32_bf16(
                        af[mt], bf[nt], acc[mt][nt], 0, 0, 0);
        }

        __syncthreads();   // drains vmcnt(0): next tile landed; cur reads done
        cur ^= 1;
    }
#undef STAGE

    // epilogue: C/D layout col=lane&15, row=(lane>>4)*4+reg
#pragma unroll
    for (int nt = 0; nt < 5; ++nt) {
        const int gc = n0 + wc + nt * 16 + lr;
        const float bv = bias[gc];
#pragma unroll
        for (int mt = 0; mt < 4; ++mt) {
#pragma unroll
            for (int r = 0; r < 4; ++r) {
                const int grow = m0 + wr + mt * 16 + quad * 4 + r;
                out[(size_t)grow * N_DIM + gc] = acc[mt][nt][r] + bv;
            }
        }
    }
}

// ---------------------------------------------------------------------------
extern "C" void kernel_launch(void* const* d_in, const int* in_sizes, int n_in,
                              void* d_out, int out_size, void* d_ws, size_t ws_size,
                              hipStream_t stream) {
    const float* x      = (const float*)d_in[0];
    const float* W      = (const float*)d_in[1];
    const float* b      = (const float*)d_in[2];
    const float* lora_A = (const float*)d_in[3];
    const float* lora_B = (const float*)d_in[4];
    float* out = (float*)d_out;

    unsigned short* Xbp = (unsigned short*)d_ws;              // 8192*1664 bf16
    unsigned short* Wtp = Xbp + (size_t)M_ROWS * KP;          // 4800*1664 bf16
    // ws bytes: (8192+4800)*1664*2 = 43,225,088

    prep_all<<<NXB + NWB + NLB, 256, 0, stream>>>(x, W, lora_A, lora_B, Xbp, Wtp);
    gemm_bt<<<dim3((N_DIM / BN) * (M_ROWS / BM)), 256, 0, stream>>>(Xbp, Wtp, b, out);
}

// Round 6
// 383.183 us; speedup vs baseline: 1.1075x; 1.0112x over previous
//
#include <hip/hip_runtime.h>
#include <hip/hip_bf16.h>

// LoRAConv1D: out[8192][4800] = x@W + b + 4.0*(x@A)@B
// Rank-8 LoRA folded into GEMM K dim (K'=1664=26*64), bf16 MFMA.
// R6: gemm reverted to the verified R2 structure EXACTLY (single-buffered
// 36 KB LDS, two barriers/K-iter, 4 waves, 12 waves/CU) + XCD-aware block
// swizzle ONLY (R4 proved it cuts FETCH 320->268 MB; R4's regression was
// its occupancy drop to 8 waves/CU, not the swizzle).
// Regime note: gemm is fetch-bound (FETCH 320 MB vs ~45 MB footprint;
// L3 thrashed by the 157 MB out stream). Sustained HBM BW scales with
// resident waves -> occupancy is sacred; traffic is the lever.

#define M_ROWS 8192
#define K_DIM  1600
#define N_DIM  4800
#define KP     1664   // 1600 + 8 (lora) + 56 zero pad = 26*64

#define BM 128
#define BN 160
#define BK 64
#define KT (KP / BK)  // 26

// fused prep grid split
#define NXB 1024              // x path: 8 rows/block (2 per wave)
#define NWB (75 * 50)         // W path: 64n x 32k tiles
#define NLB 19                // lora_B path: ceil(4800/256)

typedef __attribute__((ext_vector_type(4))) float f32x4;
typedef __attribute__((ext_vector_type(8))) short s16x8;

static __device__ __forceinline__ unsigned short f2bf(float f) {
    unsigned int u = __float_as_uint(f);
    u += 0x7fffu + ((u >> 16) & 1u);
    return (unsigned short)(u >> 16);
}

typedef __attribute__((address_space(3))) unsigned int as3_uint;
typedef __attribute__((address_space(1))) const unsigned int as1_uint;

static __device__ __forceinline__ void gl16(const unsigned short* g,
                                            unsigned short* l) {
    __builtin_amdgcn_global_load_lds((as1_uint*)g, (as3_uint*)l, 16, 0, 0);
}

// ---------------------------------------------------------------------------
// prep_all: one kernel, three block-ranges.  (unchanged from R2, verified)
//   [0, NXB)           : x -> bf16 cast + rank-8 x@A tail   (no LDS)
//   [NXB, NXB+NWB)     : W fp32 [1600][4800] -> Wtp bf16 [4800][KP] transpose
//   [NXB+NWB, +NLB)    : Wtp[n][1600..1607] = bf16(4*lora_B[r][n]); rest 0
// ---------------------------------------------------------------------------
__global__ __launch_bounds__(256) void prep_all(const float* __restrict__ x,
                                                const float* __restrict__ W,
                                                const float* __restrict__ lora_A,
                                                const float* __restrict__ lora_B,
                                                unsigned short* __restrict__ Xbp,
                                                unsigned short* __restrict__ Wtp) {
    __shared__ float tile[32][65];
    const int bid = blockIdx.x;
    const int t   = threadIdx.x;

    if (bid < NXB) {
        // ---- x path: 2 rows per wave, A from global (L2-resident) ----
        const int lane = t & 63;
        const int w    = t >> 6;
        const int m0   = bid * 8 + w * 2;
        const float* xr0 = x + (size_t)m0 * K_DIM;
        const float* xr1 = xr0 + K_DIM;
        unsigned short* o0 = Xbp + (size_t)m0 * KP;
        unsigned short* o1 = o0 + KP;

        float a0[8], a1[8];
#pragma unroll
        for (int r = 0; r < 8; ++r) { a0[r] = 0.f; a1[r] = 0.f; }

        for (int g = lane; g < 400; g += 64) {
            const float4* ap = (const float4*)(lora_A + (size_t)32 * g);
            float4 x0 = ((const float4*)xr0)[g];
            float4 x1 = ((const float4*)xr1)[g];

            ushort4 s0, s1;
            s0.x = f2bf(x0.x); s0.y = f2bf(x0.y); s0.z = f2bf(x0.z); s0.w = f2bf(x0.w);
            s1.x = f2bf(x1.x); s1.y = f2bf(x1.y); s1.z = f2bf(x1.z); s1.w = f2bf(x1.w);
            ((ushort4*)o0)[g] = s0;
            ((ushort4*)o1)[g] = s1;

            float xs0[4] = {x0.x, x0.y, x0.z, x0.w};
            float xs1[4] = {x1.x, x1.y, x1.z, x1.w};
#pragma unroll
            for (int j = 0; j < 4; ++j) {
                float4 lo = ap[2 * j + 0];
                float4 hi = ap[2 * j + 1];
                a0[0] += xs0[j] * lo.x; a0[1] += xs0[j] * lo.y;
                a0[2] += xs0[j] * lo.z; a0[3] += xs0[j] * lo.w;
                a0[4] += xs0[j] * hi.x; a0[5] += xs0[j] * hi.y;
                a0[6] += xs0[j] * hi.z; a0[7] += xs0[j] * hi.w;
                a1[0] += xs1[j] * lo.x; a1[1] += xs1[j] * lo.y;
                a1[2] += xs1[j] * lo.z; a1[3] += xs1[j] * lo.w;
                a1[4] += xs1[j] * hi.x; a1[5] += xs1[j] * hi.y;
                a1[6] += xs1[j] * hi.z; a1[7] += xs1[j] * hi.w;
            }
        }

#pragma unroll
        for (int off = 1; off < 64; off <<= 1) {
#pragma unroll
            for (int r = 0; r < 8; ++r) {
                a0[r] += __shfl_xor(a0[r], off, 64);
                a1[r] += __shfl_xor(a1[r], off, 64);
            }
        }

        if (lane < 16) {   // tail groups 400..415: [x@A | zeros]
            ushort4 t0, t1;
            t0.x = 0; t0.y = 0; t0.z = 0; t0.w = 0;
            t1 = t0;
            if (lane == 0) {
                t0.x = f2bf(a0[0]); t0.y = f2bf(a0[1]); t0.z = f2bf(a0[2]); t0.w = f2bf(a0[3]);
                t1.x = f2bf(a1[0]); t1.y = f2bf(a1[1]); t1.z = f2bf(a1[2]); t1.w = f2bf(a1[3]);
            } else if (lane == 1) {
                t0.x = f2bf(a0[4]); t0.y = f2bf(a0[5]); t0.z = f2bf(a0[6]); t0.w = f2bf(a0[7]);
                t1.x = f2bf(a1[4]); t1.y = f2bf(a1[5]); t1.z = f2bf(a1[6]); t1.w = f2bf(a1[7]);
            }
            ((ushort4*)o0)[400 + lane] = t0;
            ((ushort4*)o1)[400 + lane] = t1;
        }
        return;
    }

    if (bid < NXB + NWB) {
        // ---- W transpose path ----
        const int wid = bid - NXB;
        const int n0  = (wid % 75) * 64;
        const int k0  = (wid / 75) * 32;

#pragma unroll
        for (int p = 0; p < 2; ++p) {
            const int k  = p * 16 + (t >> 4);
            const int c4 = (t & 15) * 4;
            float4 v = *(const float4*)(W + (size_t)(k0 + k) * N_DIM + n0 + c4);
            tile[k][c4 + 0] = v.x; tile[k][c4 + 1] = v.y;
            tile[k][c4 + 2] = v.z; tile[k][c4 + 3] = v.w;
        }
        __syncthreads();

        const int n   = t >> 2;
        const int seg = t & 3;
        unsigned int pk[4];
#pragma unroll
        for (int h = 0; h < 4; ++h) {
            unsigned int lo = f2bf(tile[seg * 8 + 2 * h + 0][n]);
            unsigned int hi = f2bf(tile[seg * 8 + 2 * h + 1][n]);
            pk[h] = lo | (hi << 16);
        }
        uint4 o = {pk[0], pk[1], pk[2], pk[3]};
        *(uint4*)(Wtp + (size_t)(n0 + n) * KP + k0 + seg * 8) = o;
        return;
    }

    // ---- lora_B path ----
    {
        const int lid = bid - (NXB + NWB);
        const int n = lid * 256 + t;
        if (n >= N_DIM) return;
        ushort4* d4 = (ushort4*)(Wtp + (size_t)n * KP + 1600);
        ushort4 o0, o1, z;
        o0.x = f2bf(4.0f * lora_B[0 * N_DIM + n]);
        o0.y = f2bf(4.0f * lora_B[1 * N_DIM + n]);
        o0.z = f2bf(4.0f * lora_B[2 * N_DIM + n]);
        o0.w = f2bf(4.0f * lora_B[3 * N_DIM + n]);
        o1.x = f2bf(4.0f * lora_B[4 * N_DIM + n]);
        o1.y = f2bf(4.0f * lora_B[5 * N_DIM + n]);
        o1.z = f2bf(4.0f * lora_B[6 * N_DIM + n]);
        o1.w = f2bf(4.0f * lora_B[7 * N_DIM + n]);
        z.x = 0; z.y = 0; z.z = 0; z.w = 0;
        d4[0] = o0;
        d4[1] = o1;
#pragma unroll
        for (int i = 2; i < 16; ++i) d4[i] = z;
    }
}

// ---------------------------------------------------------------------------
// gemm_bt: C[m][n] = sum_k Ab[m][k]*Bb[n][k] + bias[n]
// R2-verified structure: 128x160 tile, 4 waves (2x2), wave tile 64x80,
// single-buffered 36 KB LDS, two __syncthreads per K-iter (12 waves/CU).
// ONLY delta vs R2: XCD-aware bijective block swizzle (1920 = 8 XCDs x
// 240; per-XCD chunk = 8 m-rows x 30 n, n fastest -> 8 A-panels = 3.4 MB
// fit the XCD's 4 MB L2). R4 measured this mapping: FETCH 320->268 MB.
// LDS layout (swizzled): row r, kgroup g stored at elem r*64 + (g^(r&7))*8;
// swizzle applied on SOURCE global address (gl_lds dst must stay linear).
// Fragment ds_read_b128 -> 2-way bank alias only (free).
// ---------------------------------------------------------------------------
__global__ __launch_bounds__(256, 3) void gemm_bt(const unsigned short* __restrict__ Ab,
                                                  const unsigned short* __restrict__ Bb,
                                                  const float* __restrict__ bias,
                                                  float* __restrict__ out) {
    __shared__ unsigned short lsA[BM * BK];   // 16 KB
    __shared__ unsigned short lsB[BN * BK];   // 20 KB

    const int t    = threadIdx.x;
    const int lane = t & 63;
    const int w    = t >> 6;

    // XCD-aware bijective swizzle: 1920 = 8 * 240
    const int bid  = blockIdx.x;
    const int swz  = (bid & 7) * 240 + (bid >> 3);
    const int m0   = (swz / 30) * BM;
    const int n0   = (swz % 30) * BN;

    const int wr   = (w >> 1) * 64;
    const int wc   = (w & 1) * 80;
    const int lr   = lane & 15;
    const int quad = lane >> 4;
    const int lx   = lr & 7;

    // staging source addressing (swizzled kgroup), chunk = 8 rows x 64 k
    const int rS = lane >> 3;                        // 0..7 within chunk
    const int gS = ((lane & 7) ^ (rS & 7)) * 8;      // source k offset
    const unsigned short* srcA = Ab + (size_t)(m0 + rS) * KP + gS;
    const unsigned short* srcB = Bb + (size_t)(n0 + rS) * KP + gS;

    int rowA[4], rowB[5];
#pragma unroll
    for (int mt = 0; mt < 4; ++mt) rowA[mt] = (wr + mt * 16 + lr) * BK;
#pragma unroll
    for (int nt = 0; nt < 5; ++nt) rowB[nt] = (wc + nt * 16 + lr) * BK;

    f32x4 acc[4][5];
#pragma unroll
    for (int mt = 0; mt < 4; ++mt)
#pragma unroll
        for (int nt = 0; nt < 5; ++nt) acc[mt][nt] = (f32x4)0.f;

    for (int kt = 0; kt < KT; ++kt) {
        const int kb = kt * BK;
        __syncthreads();   // previous iter's fragment reads complete
        // A: 16 chunks of 8 rows; B: 20 chunks — round-robin across waves
#pragma unroll
        for (int c = w; c < 16; c += 4)
            gl16(srcA + (size_t)c * 8 * KP + kb, &lsA[c * 512]);
#pragma unroll
        for (int c = w; c < 20; c += 4)
            gl16(srcB + (size_t)c * 8 * KP + kb, &lsB[c * 512]);
        __syncthreads();   // staging visible

#pragma unroll
        for (int ksub = 0; ksub < 2; ++ksub) {
            const int g0 = quad + ksub * 4;
            const int koff = ((g0 ^ lx)) * 8;
            s16x8 af[4], bf[5];
#pragma unroll
            for (int mt = 0; mt < 4; ++mt) af[mt] = *(const s16x8*)&lsA[rowA[mt] + koff];
#pragma unroll
            for (int nt = 0; nt < 5; ++nt) bf[nt] = *(const s16x8*)&lsB[rowB[nt] + koff];
#pragma unroll
            for (int mt = 0; mt < 4; ++mt)
#pragma unroll
                for (int nt = 0; nt < 5; ++nt)
                    acc[mt][nt] = __builtin_amdgcn_mfma_f32_16x16x32_bf16(
                        af[mt], bf[nt], acc[mt][nt], 0, 0, 0);
        }
    }

    // epilogue: C/D layout col=lane&15, row=(lane>>4)*4+reg
#pragma unroll
    for (int nt = 0; nt < 5; ++nt) {
        const int gc = n0 + wc + nt * 16 + lr;
        const float bv = bias[gc];
#pragma unroll
        for (int mt = 0; mt < 4; ++mt) {
#pragma unroll
            for (int r = 0; r < 4; ++r) {
                const int grow = m0 + wr + mt * 16 + quad * 4 + r;
                out[(size_t)grow * N_DIM + gc] = acc[mt][nt][r] + bv;
            }
        }
    }
}

// ---------------------------------------------------------------------------
extern "C" void kernel_launch(void* const* d_in, const int* in_sizes, int n_in,
                              void* d_out, int out_size, void* d_ws, size_t ws_size,
                              hipStream_t stream) {
    const float* x      = (const float*)d_in[0];
    const float* W      = (const float*)d_in[1];
    const float* b      = (const float*)d_in[2];
    const float* lora_A = (const float*)d_in[3];
    const float* lora_B = (const float*)d_in[4];
    float* out = (float*)d_out;

    unsigned short* Xbp = (unsigned short*)d_ws;              // 8192*1664 bf16
    unsigned short* Wtp = Xbp + (size_t)M_ROWS * KP;          // 4800*1664 bf16
    // ws bytes: (8192+4800)*1664*2 = 43,225,088

    prep_all<<<NXB + NWB + NLB, 256, 0, stream>>>(x, W, lora_A, lora_B, Xbp, Wtp);
    gemm_bt<<<dim3((N_DIM / BN) * (M_ROWS / BM)), 256, 0, stream>>>(Xbp, Wtp, b, out);
}

// Round 7
// 372.281 us; speedup vs baseline: 1.1399x; 1.0293x over previous
//
#include <hip/hip_runtime.h>
#include <hip/hip_bf16.h>

// LoRAConv1D: out[8192][4800] = x@W + b + 4.0*(x@A)@B
// Rank-8 LoRA folded into GEMM K dim (K'=1664=26*64), bf16 MFMA.
// R7: single delta vs R6 — NON-TEMPORAL epilogue stores.
// Diagnosis: gemm operand footprint is 43 MB (fits L3 6x) yet FETCH=370MB
// (8.6x refetch). The 157 MB fp32 out-stream allocates in L2/L3 and evicts
// A/B panels continuously -> every block refetches from HBM. NT stores set
// the streaming policy so the write-stream stops thrashing the caches.
// Gemm structure otherwise IDENTICAL to verified R6 (128x160, 4 waves,
// single-buffer 36KB LDS, 2 barriers/K-iter, 12 waves/CU, XCD swizzle).

#define M_ROWS 8192
#define K_DIM  1600
#define N_DIM  4800
#define KP     1664   // 1600 + 8 (lora) + 56 zero pad = 26*64

#define BM 128
#define BN 160
#define BK 64
#define KT (KP / BK)  // 26

// fused prep grid split
#define NXB 1024              // x path: 8 rows/block (2 per wave)
#define NWB (75 * 50)         // W path: 64n x 32k tiles
#define NLB 19                // lora_B path: ceil(4800/256)

typedef __attribute__((ext_vector_type(4))) float f32x4;
typedef __attribute__((ext_vector_type(8))) short s16x8;

static __device__ __forceinline__ unsigned short f2bf(float f) {
    unsigned int u = __float_as_uint(f);
    u += 0x7fffu + ((u >> 16) & 1u);
    return (unsigned short)(u >> 16);
}

typedef __attribute__((address_space(3))) unsigned int as3_uint;
typedef __attribute__((address_space(1))) const unsigned int as1_uint;

static __device__ __forceinline__ void gl16(const unsigned short* g,
                                            unsigned short* l) {
    __builtin_amdgcn_global_load_lds((as1_uint*)g, (as3_uint*)l, 16, 0, 0);
}

// ---------------------------------------------------------------------------
// prep_all: one kernel, three block-ranges.  (unchanged from R2, verified)
//   [0, NXB)           : x -> bf16 cast + rank-8 x@A tail   (no LDS)
//   [NXB, NXB+NWB)     : W fp32 [1600][4800] -> Wtp bf16 [4800][KP] transpose
//   [NXB+NWB, +NLB)    : Wtp[n][1600..1607] = bf16(4*lora_B[r][n]); rest 0
// ---------------------------------------------------------------------------
__global__ __launch_bounds__(256) void prep_all(const float* __restrict__ x,
                                                const float* __restrict__ W,
                                                const float* __restrict__ lora_A,
                                                const float* __restrict__ lora_B,
                                                unsigned short* __restrict__ Xbp,
                                                unsigned short* __restrict__ Wtp) {
    __shared__ float tile[32][65];
    const int bid = blockIdx.x;
    const int t   = threadIdx.x;

    if (bid < NXB) {
        // ---- x path: 2 rows per wave, A from global (L2-resident) ----
        const int lane = t & 63;
        const int w    = t >> 6;
        const int m0   = bid * 8 + w * 2;
        const float* xr0 = x + (size_t)m0 * K_DIM;
        const float* xr1 = xr0 + K_DIM;
        unsigned short* o0 = Xbp + (size_t)m0 * KP;
        unsigned short* o1 = o0 + KP;

        float a0[8], a1[8];
#pragma unroll
        for (int r = 0; r < 8; ++r) { a0[r] = 0.f; a1[r] = 0.f; }

        for (int g = lane; g < 400; g += 64) {
            const float4* ap = (const float4*)(lora_A + (size_t)32 * g);
            float4 x0 = ((const float4*)xr0)[g];
            float4 x1 = ((const float4*)xr1)[g];

            ushort4 s0, s1;
            s0.x = f2bf(x0.x); s0.y = f2bf(x0.y); s0.z = f2bf(x0.z); s0.w = f2bf(x0.w);
            s1.x = f2bf(x1.x); s1.y = f2bf(x1.y); s1.z = f2bf(x1.z); s1.w = f2bf(x1.w);
            ((ushort4*)o0)[g] = s0;
            ((ushort4*)o1)[g] = s1;

            float xs0[4] = {x0.x, x0.y, x0.z, x0.w};
            float xs1[4] = {x1.x, x1.y, x1.z, x1.w};
#pragma unroll
            for (int j = 0; j < 4; ++j) {
                float4 lo = ap[2 * j + 0];
                float4 hi = ap[2 * j + 1];
                a0[0] += xs0[j] * lo.x; a0[1] += xs0[j] * lo.y;
                a0[2] += xs0[j] * lo.z; a0[3] += xs0[j] * lo.w;
                a0[4] += xs0[j] * hi.x; a0[5] += xs0[j] * hi.y;
                a0[6] += xs0[j] * hi.z; a0[7] += xs0[j] * hi.w;
                a1[0] += xs1[j] * lo.x; a1[1] += xs1[j] * lo.y;
                a1[2] += xs1[j] * lo.z; a1[3] += xs1[j] * lo.w;
                a1[4] += xs1[j] * hi.x; a1[5] += xs1[j] * hi.y;
                a1[6] += xs1[j] * hi.z; a1[7] += xs1[j] * hi.w;
            }
        }

#pragma unroll
        for (int off = 1; off < 64; off <<= 1) {
#pragma unroll
            for (int r = 0; r < 8; ++r) {
                a0[r] += __shfl_xor(a0[r], off, 64);
                a1[r] += __shfl_xor(a1[r], off, 64);
            }
        }

        if (lane < 16) {   // tail groups 400..415: [x@A | zeros]
            ushort4 t0, t1;
            t0.x = 0; t0.y = 0; t0.z = 0; t0.w = 0;
            t1 = t0;
            if (lane == 0) {
                t0.x = f2bf(a0[0]); t0.y = f2bf(a0[1]); t0.z = f2bf(a0[2]); t0.w = f2bf(a0[3]);
                t1.x = f2bf(a1[0]); t1.y = f2bf(a1[1]); t1.z = f2bf(a1[2]); t1.w = f2bf(a1[3]);
            } else if (lane == 1) {
                t0.x = f2bf(a0[4]); t0.y = f2bf(a0[5]); t0.z = f2bf(a0[6]); t0.w = f2bf(a0[7]);
                t1.x = f2bf(a1[4]); t1.y = f2bf(a1[5]); t1.z = f2bf(a1[6]); t1.w = f2bf(a1[7]);
            }
            ((ushort4*)o0)[400 + lane] = t0;
            ((ushort4*)o1)[400 + lane] = t1;
        }
        return;
    }

    if (bid < NXB + NWB) {
        // ---- W transpose path ----
        const int wid = bid - NXB;
        const int n0  = (wid % 75) * 64;
        const int k0  = (wid / 75) * 32;

#pragma unroll
        for (int p = 0; p < 2; ++p) {
            const int k  = p * 16 + (t >> 4);
            const int c4 = (t & 15) * 4;
            float4 v = *(const float4*)(W + (size_t)(k0 + k) * N_DIM + n0 + c4);
            tile[k][c4 + 0] = v.x; tile[k][c4 + 1] = v.y;
            tile[k][c4 + 2] = v.z; tile[k][c4 + 3] = v.w;
        }
        __syncthreads();

        const int n   = t >> 2;
        const int seg = t & 3;
        unsigned int pk[4];
#pragma unroll
        for (int h = 0; h < 4; ++h) {
            unsigned int lo = f2bf(tile[seg * 8 + 2 * h + 0][n]);
            unsigned int hi = f2bf(tile[seg * 8 + 2 * h + 1][n]);
            pk[h] = lo | (hi << 16);
        }
        uint4 o = {pk[0], pk[1], pk[2], pk[3]};
        *(uint4*)(Wtp + (size_t)(n0 + n) * KP + k0 + seg * 8) = o;
        return;
    }

    // ---- lora_B path ----
    {
        const int lid = bid - (NXB + NWB);
        const int n = lid * 256 + t;
        if (n >= N_DIM) return;
        ushort4* d4 = (ushort4*)(Wtp + (size_t)n * KP + 1600);
        ushort4 o0, o1, z;
        o0.x = f2bf(4.0f * lora_B[0 * N_DIM + n]);
        o0.y = f2bf(4.0f * lora_B[1 * N_DIM + n]);
        o0.z = f2bf(4.0f * lora_B[2 * N_DIM + n]);
        o0.w = f2bf(4.0f * lora_B[3 * N_DIM + n]);
        o1.x = f2bf(4.0f * lora_B[4 * N_DIM + n]);
        o1.y = f2bf(4.0f * lora_B[5 * N_DIM + n]);
        o1.z = f2bf(4.0f * lora_B[6 * N_DIM + n]);
        o1.w = f2bf(4.0f * lora_B[7 * N_DIM + n]);
        z.x = 0; z.y = 0; z.z = 0; z.w = 0;
        d4[0] = o0;
        d4[1] = o1;
#pragma unroll
        for (int i = 2; i < 16; ++i) d4[i] = z;
    }
}

// ---------------------------------------------------------------------------
// gemm_bt: C[m][n] = sum_k Ab[m][k]*Bb[n][k] + bias[n]
// R2-verified structure: 128x160 tile, 4 waves (2x2), wave tile 64x80,
// single-buffered 36 KB LDS, two __syncthreads per K-iter (12 waves/CU).
// XCD swizzle (1920 = 8 x 240) kept from R6.
// R7 delta: epilogue stores are NON-TEMPORAL (streaming policy) so the
// 157 MB out-stream does not allocate in / evict A,B from L2+L3.
// LDS layout (swizzled): row r, kgroup g stored at elem r*64 + (g^(r&7))*8;
// swizzle applied on SOURCE global address (gl_lds dst must stay linear).
// Fragment ds_read_b128 -> 2-way bank alias only (free).
// ---------------------------------------------------------------------------
__global__ __launch_bounds__(256, 3) void gemm_bt(const unsigned short* __restrict__ Ab,
                                                  const unsigned short* __restrict__ Bb,
                                                  const float* __restrict__ bias,
                                                  float* __restrict__ out) {
    __shared__ unsigned short lsA[BM * BK];   // 16 KB
    __shared__ unsigned short lsB[BN * BK];   // 20 KB

    const int t    = threadIdx.x;
    const int lane = t & 63;
    const int w    = t >> 6;

    // XCD-aware bijective swizzle: 1920 = 8 * 240
    const int bid  = blockIdx.x;
    const int swz  = (bid & 7) * 240 + (bid >> 3);
    const int m0   = (swz / 30) * BM;
    const int n0   = (swz % 30) * BN;

    const int wr   = (w >> 1) * 64;
    const int wc   = (w & 1) * 80;
    const int lr   = lane & 15;
    const int quad = lane >> 4;
    const int lx   = lr & 7;

    // staging source addressing (swizzled kgroup), chunk = 8 rows x 64 k
    const int rS = lane >> 3;                        // 0..7 within chunk
    const int gS = ((lane & 7) ^ (rS & 7)) * 8;      // source k offset
    const unsigned short* srcA = Ab + (size_t)(m0 + rS) * KP + gS;
    const unsigned short* srcB = Bb + (size_t)(n0 + rS) * KP + gS;

    int rowA[4], rowB[5];
#pragma unroll
    for (int mt = 0; mt < 4; ++mt) rowA[mt] = (wr + mt * 16 + lr) * BK;
#pragma unroll
    for (int nt = 0; nt < 5; ++nt) rowB[nt] = (wc + nt * 16 + lr) * BK;

    f32x4 acc[4][5];
#pragma unroll
    for (int mt = 0; mt < 4; ++mt)
#pragma unroll
        for (int nt = 0; nt < 5; ++nt) acc[mt][nt] = (f32x4)0.f;

    for (int kt = 0; kt < KT; ++kt) {
        const int kb = kt * BK;
        __syncthreads();   // previous iter's fragment reads complete
        // A: 16 chunks of 8 rows; B: 20 chunks — round-robin across waves
#pragma unroll
        for (int c = w; c < 16; c += 4)
            gl16(srcA + (size_t)c * 8 * KP + kb, &lsA[c * 512]);
#pragma unroll
        for (int c = w; c < 20; c += 4)
            gl16(srcB + (size_t)c * 8 * KP + kb, &lsB[c * 512]);
        __syncthreads();   // staging visible

#pragma unroll
        for (int ksub = 0; ksub < 2; ++ksub) {
            const int g0 = quad + ksub * 4;
            const int koff = ((g0 ^ lx)) * 8;
            s16x8 af[4], bf[5];
#pragma unroll
            for (int mt = 0; mt < 4; ++mt) af[mt] = *(const s16x8*)&lsA[rowA[mt] + koff];
#pragma unroll
            for (int nt = 0; nt < 5; ++nt) bf[nt] = *(const s16x8*)&lsB[rowB[nt] + koff];
#pragma unroll
            for (int mt = 0; mt < 4; ++mt)
#pragma unroll
                for (int nt = 0; nt < 5; ++nt)
                    acc[mt][nt] = __builtin_amdgcn_mfma_f32_16x16x32_bf16(
                        af[mt], bf[nt], acc[mt][nt], 0, 0, 0);
        }
    }

    // epilogue: C/D layout col=lane&15, row=(lane>>4)*4+reg
    // NT stores: streaming policy, don't allocate in L2/L3.
#pragma unroll
    for (int nt = 0; nt < 5; ++nt) {
        const int gc = n0 + wc + nt * 16 + lr;
        const float bv = bias[gc];
#pragma unroll
        for (int mt = 0; mt < 4; ++mt) {
#pragma unroll
            for (int r = 0; r < 4; ++r) {
                const int grow = m0 + wr + mt * 16 + quad * 4 + r;
                __builtin_nontemporal_store(acc[mt][nt][r] + bv,
                                            &out[(size_t)grow * N_DIM + gc]);
            }
        }
    }
}

// ---------------------------------------------------------------------------
extern "C" void kernel_launch(void* const* d_in, const int* in_sizes, int n_in,
                              void* d_out, int out_size, void* d_ws, size_t ws_size,
                              hipStream_t stream) {
    const float* x      = (const float*)d_in[0];
    const float* W      = (const float*)d_in[1];
    const float* b      = (const float*)d_in[2];
    const float* lora_A = (const float*)d_in[3];
    const float* lora_B = (const float*)d_in[4];
    float* out = (float*)d_out;

    unsigned short* Xbp = (unsigned short*)d_ws;              // 8192*1664 bf16
    unsigned short* Wtp = Xbp + (size_t)M_ROWS * KP;          // 4800*1664 bf16
    // ws bytes: (8192+4800)*1664*2 = 43,225,088

    prep_all<<<NXB + NWB + NLB, 256, 0, stream>>>(x, W, lora_A, lora_B, Xbp, Wtp);
    gemm_bt<<<dim3((N_DIM / BN) * (M_ROWS / BM)), 256, 0, stream>>>(Xbp, Wtp, b, out);
}